// Round 13
// baseline (252.440 us; speedup 1.0000x reference)
//
#include <hip/hip_runtime.h>
#include <hip/hip_bf16.h>
#include <math.h>

#define DIM   2048
#define S_LEN 2048
#define BATCH 2
#define NH    16
#define NKV   4
#define CQ_   128
#define QN_   96
#define QR_   32
#define CKV_  128
#define KN_   64
#define KR_   64
#define VD_   256
#define DQK   192
#define DV    128
#define ROWS_TOT (BATCH*S_LEN)   // 4096
#define QK_SCALE 0.08838834764831845f
#define LOG2E    1.4426950408889634f

typedef __attribute__((ext_vector_type(8)))  short short8;
typedef __attribute__((ext_vector_type(4)))  short short4v;
typedef __attribute__((ext_vector_type(4)))  float float4v;
typedef __attribute__((ext_vector_type(16))) float float16v;
typedef __attribute__((ext_vector_type(4)))  int   int4v;

__device__ inline short f2bf(float x) {
    union { __hip_bfloat16 h; short s; } u;
    u.h = __float2bfloat16(x);
    return u.s;
}

__device__ __forceinline__ void gl_lds16(const short* g, short* lds) {
    __builtin_amdgcn_global_load_lds(
        (const __attribute__((address_space(1))) unsigned int*)(g),
        (__attribute__((address_space(3))) unsigned int*)(lds),
        16, 0, 0);
}

__device__ __forceinline__ short8 cast8(const float* p) {
    float4 a = *reinterpret_cast<const float4*>(p);
    float4 b = *reinterpret_cast<const float4*>(p + 4);
    short8 o;
    o[0] = f2bf(a.x); o[1] = f2bf(a.y); o[2] = f2bf(a.z); o[3] = f2bf(a.w);
    o[4] = f2bf(b.x); o[5] = f2bf(b.y); o[6] = f2bf(b.z); o[7] = f2bf(b.w);
    return o;
}

// ---------------------------------------------------------------------------
// KW: ALL weight prep in one launch (no w_oT intermediate).
//   [0,160)    : [w_dq|w_dkv] -> wdT (320x2048)
//   [160,224)  : w_uq -> w_uqT (2048x128)
//   [224,608)  : RoPE tables tq (S,16,2), tk (S,32,2)
//   [608,624)  : WqcombT[h] = w_ukv_k[·,kvh]^T x w_uq_nopeA[·,h]  (128x128, K=64)
//   [624,880)  : WcombT (h,nt): stage w_o 256x128 f32 block -> LDS bf16
//                transposed, then WcombT[n, h*128+c] = sum_d woT[n,d]*wv[c,d]
// ---------------------------------------------------------------------------
__global__ __launch_bounds__(256)
void kw_prep(const float* __restrict__ w_o, const float* __restrict__ w_uq,
             const float* __restrict__ w_ukv, const float* __restrict__ w_dq,
             const float* __restrict__ w_dkv,
             short* __restrict__ wdT, short* __restrict__ w_uqT,
             short* __restrict__ WqcombT, short* __restrict__ WcombT,
             float* __restrict__ tq, float* __restrict__ tk)
{
    __shared__ char smem[67584];   // union: tf[64][65] f32 | wot[128][264] bf16
    const int bid = blockIdx.x, tid = threadIdx.x;
    const int lane = tid & 63, wid = tid >> 6;
    const int g = lane >> 4, l15 = lane & 15;

    if (bid < 224) {   // ---- transposes: wdT, w_uqT ----
        float* tf = (float*)smem;          // [64][65]
        int lb, nct, R; short* dst;
        if (bid < 160) { lb = bid;       nct = 5;  R = 2048; dst = wdT;   }
        else           { lb = bid - 160; nct = 32; R = 128;  dst = w_uqT; }
        const int ct = lb % nct, rt = lb / nct;
        const int r0 = rt * 64, c0 = ct * 64;
        const float* src; int stride, nbase;
        if (bid < 160) {
            if (ct < 2) { src = w_dq;  stride = 128; nbase = c0; }
            else        { src = w_dkv; stride = 192; nbase = c0 - 128; }
        } else { src = w_uq; stride = 2048; nbase = c0; }

        #pragma unroll
        for (int u4 = 0; u4 < 4; ++u4) {
            int u = u4 * 256 + tid;
            int kr = u >> 4, nc = (u & 15) * 4;
            float4 v = *reinterpret_cast<const float4*>(&src[(size_t)(r0 + kr) * stride + nbase + nc]);
            tf[kr * 65 + nc + 0] = v.x; tf[kr * 65 + nc + 1] = v.y;
            tf[kr * 65 + nc + 2] = v.z; tf[kr * 65 + nc + 3] = v.w;
        }
        __syncthreads();
        #pragma unroll
        for (int u2 = 0; u2 < 2; ++u2) {
            int u = u2 * 256 + tid;
            int nr = u >> 3, kc8 = (u & 7) * 8;
            short8 o;
            #pragma unroll
            for (int j = 0; j < 8; ++j) o[j] = f2bf(tf[(kc8 + j) * 65 + nr]);
            *reinterpret_cast<short8*>(&dst[(size_t)(c0 + nr) * R + r0 + kc8]) = o;
        }
        return;
    }
    if (bid < 608) {   // ---- RoPE tables ----
        int gid = (bid - 224) * 256 + tid;
        int spos = gid / 48, e = gid - spos * 48;
        if (e < 16) {
            float inv = powf(10000.f, -(float)(2 * e) / 32.f);
            float sn, c; sincosf((float)spos * inv, &sn, &c);
            tq[(spos * 16 + e) * 2 + 0] = c;
            tq[(spos * 16 + e) * 2 + 1] = sn;
        } else {
            int i2 = e - 16;
            float inv = powf(10000.f, -(float)(2 * i2) / 64.f);
            float sn, c; sincosf((float)spos * inv, &sn, &c);
            tk[(spos * 32 + i2) * 2 + 0] = c;
            tk[(spos * 32 + i2) * 2 + 1] = sn;
        }
        return;
    }
    if (bid < 624) {   // ---- WqcombT (16 blocks, K=64) ----
        const int h = bid - 608, kvh = h >> 2;
        float4v acc[2][8];
        #pragma unroll
        for (int mi = 0; mi < 2; ++mi)
            #pragma unroll
            for (int nj = 0; nj < 8; ++nj) acc[mi][nj] = (float4v){0.f, 0.f, 0.f, 0.f};
        #pragma unroll
        for (int kb = 0; kb < 2; ++kb) {
            short8 af[2], bf[8];
            #pragma unroll
            for (int mi = 0; mi < 2; ++mi) {
                int j = wid * 32 + mi * 16 + l15;
                af[mi] = cast8(&w_ukv[(size_t)j * 1280 + kvh * 64 + kb * 32 + g * 8]);
            }
            #pragma unroll
            for (int nj = 0; nj < 8; ++nj) {
                int e = nj * 16 + l15;
                bf[nj] = cast8(&w_uq[(size_t)e * 2048 + h * 96 + kb * 32 + g * 8]);
            }
            #pragma unroll
            for (int mi = 0; mi < 2; ++mi)
                #pragma unroll
                for (int nj = 0; nj < 8; ++nj)
                    acc[mi][nj] = __builtin_amdgcn_mfma_f32_16x16x32_bf16(
                        af[mi], bf[nj], acc[mi][nj], 0, 0, 0);
        }
        #pragma unroll
        for (int mi = 0; mi < 2; ++mi)
            #pragma unroll
            for (int nj = 0; nj < 8; ++nj)
                #pragma unroll
                for (int r = 0; r < 4; ++r)
                    WqcombT[(size_t)h * 16384 + (wid * 32 + mi * 16 + g * 4 + r) * 128
                            + nj * 16 + l15] = f2bf(acc[mi][nj][r]);
        return;
    }

    // ---- WcombT (256 blocks): direct from w_o via LDS-transposed stage ----
    {
        const int bb = bid - 624;
        const int h = bb >> 4, nt = bb & 15, kvh = h >> 2;
        const int wm = wid >> 1, wn = wid & 1;
        short* wot = (short*)smem;   // [128][264] bf16, padded

        // stage w_o[h*256 + r][nt*128 + c] -> wot[c][r]  (8192 float4)
        for (int u = tid; u < 8192; u += 256) {
            int r = u >> 5, c4 = (u & 31) * 4;
            float4 v = *reinterpret_cast<const float4*>(
                &w_o[(size_t)(h * 256 + r) * DIM + nt * 128 + c4]);
            wot[(c4 + 0) * 264 + r] = f2bf(v.x);
            wot[(c4 + 1) * 264 + r] = f2bf(v.y);
            wot[(c4 + 2) * 264 + r] = f2bf(v.z);
            wot[(c4 + 3) * 264 + r] = f2bf(v.w);
        }
        __syncthreads();

        float4v acc[4][4];
        #pragma unroll
        for (int mi = 0; mi < 4; ++mi)
            #pragma unroll
            for (int nj = 0; nj < 4; ++nj) acc[mi][nj] = (float4v){0.f, 0.f, 0.f, 0.f};
        for (int kb = 0; kb < 8; ++kb) {
            short8 af[4], bf[4];
            #pragma unroll
            for (int mi = 0; mi < 4; ++mi) {
                int nl = wm * 64 + mi * 16 + l15;
                af[mi] = *reinterpret_cast<const short8*>(
                    &wot[nl * 264 + kb * 32 + g * 8]);
            }
            #pragma unroll
            for (int nj = 0; nj < 4; ++nj) {
                int c = wn * 64 + nj * 16 + l15;
                bf[nj] = cast8(&w_ukv[(size_t)c * 1280 + 256 + kvh * 256 + kb * 32 + g * 8]);
            }
            #pragma unroll
            for (int mi = 0; mi < 4; ++mi)
                #pragma unroll
                for (int nj = 0; nj < 4; ++nj)
                    acc[mi][nj] = __builtin_amdgcn_mfma_f32_16x16x32_bf16(
                        af[mi], bf[nj], acc[mi][nj], 0, 0, 0);
        }
        #pragma unroll
        for (int mi = 0; mi < 4; ++mi)
            #pragma unroll
            for (int nj = 0; nj < 4; ++nj)
                #pragma unroll
                for (int r = 0; r < 4; ++r)
                    WcombT[(size_t)(nt * 128 + wm * 64 + mi * 16 + g * 4 + r) * 2048
                           + h * 128 + wn * 64 + nj * 16 + l15] = f2bf(acc[mi][nj][r]);
    }
}

// ---------------------------------------------------------------------------
// K12: fused down-proj + LN + K-RoPE + kx images + absorbed Q up-proj + Q-RoPE.
//   Per block: m-tile of 16 rows. cq never leaves the block (LDS bf16).
// ---------------------------------------------------------------------------
__global__ __launch_bounds__(256)
void k12_mfma(const float* __restrict__ x, const short* __restrict__ wdT,
              const float* __restrict__ gamma_q, const float* __restrict__ gamma_kv,
              const float* __restrict__ tk, const float* __restrict__ tq,
              const short* __restrict__ WqcombT, const short* __restrict__ w_uqT,
              short* __restrict__ kimg, short* __restrict__ vimg,
              short* __restrict__ q_states)
{
    __shared__ float ys[16][321];
    __shared__ float st[16][4];
    __shared__ short cqs[16][136];   // padded: 2-way banks on frag reads
    const int tid = threadIdx.x, lane = tid & 63, w = tid >> 6;
    const int g = lane >> 4, l15 = lane & 15;
    const int m0 = blockIdx.x * 16;
    const int wn0 = w * 80;

    float4v acc5[5];
    #pragma unroll
    for (int nj = 0; nj < 5; ++nj) acc5[nj] = (float4v){0.f, 0.f, 0.f, 0.f};

    const float* arow = x + (size_t)(m0 + l15) * 2048 + g * 8;
    for (int ks = 0; ks < 64; ++ks) {
        short8 a = cast8(arow + ks * 32);
        #pragma unroll
        for (int nj = 0; nj < 5; ++nj) {
            short8 bf = *reinterpret_cast<const short8*>(
                wdT + (size_t)(wn0 + nj * 16 + l15) * 2048 + ks * 32 + g * 8);
            acc5[nj] = __builtin_amdgcn_mfma_f32_16x16x32_bf16(a, bf, acc5[nj], 0, 0, 0);
        }
    }

    #pragma unroll
    for (int nj = 0; nj < 5; ++nj)
        #pragma unroll
        for (int r = 0; r < 4; ++r)
            ys[g * 4 + r][wn0 + nj * 16 + l15] = acc5[nj][r];
    __syncthreads();

    if (tid < 32) {
        int row = tid >> 1, seg = tid & 1, base = seg * 128;
        float s1 = 0.f, s2 = 0.f;
        for (int j = 0; j < 128; ++j) { float v = ys[row][base + j]; s1 += v; s2 += v * v; }
        float mu  = s1 * (1.f / 128.f);
        float var = s2 * (1.f / 128.f) - mu * mu;
        st[row][seg * 2 + 0] = mu;
        st[row][seg * 2 + 1] = rsqrtf(var + 1e-5f);
    }
    __syncthreads();

    // cq (scaled) -> LDS bf16
    for (int i = tid; i < 16 * 128; i += 256) {
        int row = i >> 7, col = i & 127;
        cqs[row][col] =
            f2bf((ys[row][col] - st[row][0]) * st[row][1] * gamma_q[col] * (QK_SCALE * LOG2E));
    }
    // kx images
    for (int i = tid; i < 16 * 192; i += 256) {
        int row = i / 192, d = i - row * 192;
        int r = m0 + row, b = r >> 11, spos = r & (S_LEN - 1);
        int tile = b * 32 + (spos >> 6);
        if (d < 128) {
            float val = (ys[row][128 + d] - st[row][2]) * st[row][3] * gamma_kv[d];
            short v_ = f2bf(val);
            size_t vslot = (d >> 5) * 256 + ((spos >> 5) & 1) * 128
                           + ((spos >> 4) & 1) * 64 + ((spos >> 3) & 1) * 32 + (d & 31);
            vimg[((size_t)tile * 1024 + vslot) * 8 + (spos & 7)] = v_;
            size_t kslot = ((spos >> 5) & 1) * 768 + (d >> 4) * 64
                           + ((d >> 3) & 1) * 32 + (spos & 31);
            kimg[((size_t)tile * 1536 + kslot) * 8 + (d & 7)] = v_;
        } else {
            int dd = d - 128, i2 = dd >> 1;
            float xe = ys[row][256 + (dd & ~1)];
            float xo = ys[row][256 + (dd | 1)];
            float c  = tk[(spos * 32 + i2) * 2 + 0];
            float sn = tk[(spos * 32 + i2) * 2 + 1];
            float val = (dd & 1) ? (xe * sn + xo * c) : (xe * c - xo * sn);
            size_t kslot = ((spos >> 5) & 1) * 768 + (d >> 4) * 64
                           + ((d >> 3) & 1) * 32 + (spos & 31);
            kimg[((size_t)tile * 1536 + kslot) * 8 + (d & 7)] = f2bf(val);
        }
    }
    __syncthreads();

    // ---- absorbed Q up-projection: 3 chunks of 1024 cols ----
    short8 af[4];
    #pragma unroll
    for (int ks = 0; ks < 4; ++ks)
        af[ks] = *reinterpret_cast<const short8*>(&cqs[l15][ks * 32 + g * 8]);

    for (int ns = 0; ns < 3; ++ns) {
        const int nb = ns * 1024 + w * 256;
        float4v acc[16];
        #pragma unroll
        for (int nj = 0; nj < 16; ++nj) acc[nj] = (float4v){0.f, 0.f, 0.f, 0.f};

        #pragma unroll
        for (int ks = 0; ks < 4; ++ks)
            #pragma unroll
            for (int nj = 0; nj < 16; ++nj) {
                int j = nb + nj * 16 + l15;
                int h = j / 192, t = j - h * 192;
                const short* brow;
                if (t < 128)       brow = WqcombT + (size_t)h * 16384 + (size_t)t * 128;
                else if (t < 160)  brow = w_uqT + (size_t)(h * 96 + 64 + (t - 128)) * 128;
                else               brow = w_uqT + (size_t)(1536 + h * 32 + (t - 160)) * 128;
                short8 bf = *reinterpret_cast<const short8*>(brow + ks * 32 + g * 8);
                acc[nj] = __builtin_amdgcn_mfma_f32_16x16x32_bf16(af[ks], bf, acc[nj], 0, 0, 0);
            }

        #pragma unroll
        for (int nj = 0; nj < 16; ++nj) {
            int j = nb + nj * 16 + l15;
            int h = j / 192, t = j - h * 192;
            if (t < 160) {
                #pragma unroll
                for (int r = 0; r < 4; ++r) {
                    int rg = m0 + g * 4 + r, bb = rg >> 11, spos = rg & (S_LEN - 1);
                    q_states[((size_t)(bb * NH + h) * S_LEN + spos) * DQK + t] =
                        f2bf(acc[nj][r]);
                }
            } else {
                int dd = t - 160, i2 = dd >> 1;
                #pragma unroll
                for (int r = 0; r < 4; ++r) {
                    int rg = m0 + g * 4 + r, bb = rg >> 11, spos = rg & (S_LEN - 1);
                    float v = acc[nj][r];
                    float p = __shfl_xor(v, 1, 64);
                    float c  = tq[(spos * 16 + i2) * 2 + 0];
                    float sn = tq[(spos * 16 + i2) * 2 + 1];
                    float out = (dd & 1) ? (p * sn + v * c) : (v * c - p * sn);
                    q_states[((size_t)(bb * NH + h) * S_LEN + spos) * DQK + t] = f2bf(out);
                }
            }
        }
    }
}

// ---------------------------------------------------------------------------
// K4: absorbed-MLA swapped-QK 32x32 MFMA flash attention (R12-proven, verbatim).
// ---------------------------------------------------------------------------
__global__ __launch_bounds__(512, 1)
void k4_attn_mfma(const short* __restrict__ q_states,
                  const short* __restrict__ kimg,
                  const short* __restrict__ vimg,
                  short* __restrict__ attn_out)
{
    __shared__ __align__(16) short ks_lds[3][12288];   // 3 x 24 KB
    __shared__ __align__(16) short vt_lds[2][8192];    // 2 x 16 KB

    const int tid = threadIdx.x, lane = tid & 63, w = tid >> 6;
    const int bid = blockIdx.x;
    const int l31 = lane & 31, hi = lane >> 5;
    const int g = w & 3, h = w >> 2;
    const int qt = (bid < 256) ? (15 - (bid >> 5)) : (7 - ((bid - 256) >> 5));
    const int bh = bid & 31;
    const int h_head = bh & 15, b = bh >> 4;

    const short* kfbase = kimg + (size_t)b * 32 * 12288;
    const short* vfbase = vimg + (size_t)b * 32 * 8192;

    const int qrow0 = qt * 128 + g * 32;
    const int qglob = qrow0 + l31;

    short8 qcur[12];
    {
        const short* qr = q_states +
            ((size_t)(b * NH + h_head) * S_LEN + qglob) * DQK + hi * 8;
        #pragma unroll
        for (int st = 0; st < 12; ++st)
            qcur[st] = *reinterpret_cast<const short8*>(qr + st * 16);
    }

    float16v o[4];
    #pragma unroll
    for (int dt = 0; dt < 4; ++dt)
        #pragma unroll
        for (int r = 0; r < 16; ++r) o[dt][r] = 0.f;
    float mreg = -1e30f, lreg = 0.f;

    const int nkt = 2 * (qt + 1);

    auto issueK = [&](int kt, int bufi) {
        const short* src = kfbase + (size_t)kt * 12288;
        #pragma unroll
        for (int i = 0; i < 3; ++i) {
            int c = w * 3 + i;
            gl_lds16(src + c * 512 + lane * 8, &ks_lds[bufi][c * 512]);
        }
    };
    auto issueV = [&](int kt, int bufi) {
        const short* src = vfbase + (size_t)kt * 8192;
        #pragma unroll
        for (int i = 0; i < 2; ++i) {
            int c = w * 2 + i;
            gl_lds16(src + c * 512 + lane * 8, &vt_lds[bufi][c * 512]);
        }
    };

    issueK(0, 0);
    issueV(0, 0);
    issueK(1, 1);

    for (int seq = 0; seq < nkt; ++seq) {
        if (seq < nkt - 1) { asm volatile("s_waitcnt vmcnt(3)" ::: "memory"); }
        else               { asm volatile("s_waitcnt vmcnt(0)" ::: "memory"); }
        __builtin_amdgcn_s_barrier();
        __builtin_amdgcn_sched_barrier(0);

        if (seq + 1 < nkt) issueV(seq + 1, (seq + 1) & 1);
        if (seq + 2 < nkt) issueK(seq + 2, (seq + 2) % 3);

        const int kvb = seq * 64 + h * 32;
        if (kvb <= qrow0 + 31) {
            const short* kbuf = &ks_lds[seq % 3][h * 6144];
            float16v sa, sb;
            #pragma unroll
            for (int r = 0; r < 16; ++r) { sa[r] = 0.f; sb[r] = 0.f; }
            __builtin_amdgcn_s_setprio(1);
            #pragma unroll
            for (int st = 0; st < 12; st += 2) {
                short8 kf0 = *reinterpret_cast<const short8*>(kbuf + st * 512 + lane * 8);
                sa = __builtin_amdgcn_mfma_f32_32x32x16_bf16(kf0, qcur[st], sa, 0, 0, 0);
                short8 kf1 = *reinterpret_cast<const short8*>(kbuf + (st + 1) * 512 + lane * 8);
                sb = __builtin_amdgcn_mfma_f32_32x32x16_bf16(kf1, qcur[st + 1], sb, 0, 0, 0);
            }
            __builtin_amdgcn_s_setprio(0);
            float16v s;
            #pragma unroll
            for (int r = 0; r < 16; ++r) s[r] = sa[r] + sb[r];

            if (kvb + 31 > qrow0) {
                #pragma unroll
                for (int r = 0; r < 16; ++r) {
                    int kc = kvb + ((r & 3) + 8 * (r >> 2) + 4 * hi);
                    if (kc > qglob) s[r] = -1e30f;
                }
            }

            float mx = s[0];
            #pragma unroll
            for (int r = 1; r < 16; ++r) mx = fmaxf(mx, s[r]);
            mx = fmaxf(mx, __shfl_xor(mx, 32, 64));
            bool need = mx > mreg + 8.f;
            if (__ballot(need)) {
                float mnew = fmaxf(mreg, mx);
                float corr = exp2f(mreg - mnew);
                mreg = mnew;
                lreg *= corr;
                #pragma unroll
                for (int dt = 0; dt < 4; ++dt)
                    #pragma unroll
                    for (int r = 0; r < 16; ++r) o[dt][r] *= corr;
            }
            #pragma unroll
            for (int r = 0; r < 16; ++r) s[r] = exp2f(s[r] - mreg);
            float ps = 0.f;
            #pragma unroll
            for (int r = 0; r < 16; ++r) ps += s[r];
            ps += __shfl_xor(ps, 32, 64);
            lreg += ps;

            const short* vbuf = &vt_lds[seq & 1][h * 1024];
            __builtin_amdgcn_s_setprio(1);
            #pragma unroll
            for (int ks = 0; ks < 2; ++ks) {
                const int rb = ks * 8;
                int c01, c23, c45, c67;
                asm("v_cvt_pk_bf16_f32 %0, %1, %2" : "=v"(c01) : "v"(s[rb+0]), "v"(s[rb+1]));
                asm("v_cvt_pk_bf16_f32 %0, %1, %2" : "=v"(c23) : "v"(s[rb+2]), "v"(s[rb+3]));
                asm("v_cvt_pk_bf16_f32 %0, %1, %2" : "=v"(c45) : "v"(s[rb+4]), "v"(s[rb+5]));
                asm("v_cvt_pk_bf16_f32 %0, %1, %2" : "=v"(c67) : "v"(s[rb+6]), "v"(s[rb+7]));
                asm("v_permlane32_swap_b32 %0, %1" : "+v"(c01), "+v"(c45));
                asm("v_permlane32_swap_b32 %0, %1" : "+v"(c23), "+v"(c67));
                union { int4v i4; short8 s8; } u_;
                u_.i4.x = c01; u_.i4.y = c23; u_.i4.z = c45; u_.i4.w = c67;
                short8 pa = u_.s8;
                #pragma unroll
                for (int dt = 0; dt < 4; ++dt) {
                    short8 vf = *reinterpret_cast<const short8*>(
                        vbuf + dt * 2048 + ks * 512 + lane * 8);
                    o[dt] = __builtin_amdgcn_mfma_f32_32x32x16_bf16(vf, pa, o[dt], 0, 0, 0);
                }
            }
            __builtin_amdgcn_s_setprio(0);
        }
    }

    __syncthreads();
    {
        float* mlb = (float*)(&ks_lds[0][0]);
        mlb[w * 64 + lane] = mreg;
        mlb[512 + w * 64 + lane] = lreg;
    }
    __syncthreads();
    float s0f = 0.f, s1f = 0.f;
    if (h == 0) {
        float* mlb = (float*)(&ks_lds[0][0]);
        float m1 = mlb[(w + 4) * 64 + lane];
        float l1 = mlb[512 + (w + 4) * 64 + lane];
        float ms = fmaxf(mreg, m1);
        float c0 = exp2f(mreg - ms), c1 = exp2f(m1 - ms);
        float ls = lreg * c0 + l1 * c1;
        s0f = c0 / ls; s1f = c1 / ls;
    }
    float* cb = (float*)(&ks_lds[0][0]) + 1024;
    short* obase = attn_out + ((size_t)(b * S_LEN + qglob)) * 2048 + h_head * 128;
    for (int dt = 0; dt < 4; ++dt) {
        __syncthreads();
        if (h == 1) {
            #pragma unroll
            for (int r = 0; r < 16; ++r)
                cb[r * 256 + g * 64 + lane] = o[dt][r];
        }
        __syncthreads();
        if (h == 0) {
            #pragma unroll
            for (int r = 0; r < 16; ++r)
                o[dt][r] = o[dt][r] * s0f + cb[r * 256 + g * 64 + lane] * s1f;
            #pragma unroll
            for (int k4i = 0; k4i < 4; ++k4i) {
                int d0 = dt * 32 + k4i * 8 + hi * 4;
                short4v pk;
                #pragma unroll
                for (int j = 0; j < 4; ++j) pk[j] = f2bf(o[dt][k4i * 4 + j]);
                *reinterpret_cast<short4v*>(obase + d0) = pk;
            }
        }
    }
}

// ---------------------------------------------------------------------------
// K5: out = attn_out (4096x2048 bf16) @ WcombT (2048x2048 bf16), f32 out.
// ---------------------------------------------------------------------------
__global__ __launch_bounds__(256)
void k5_gemm_mfma(const short* __restrict__ A,
                  const short* __restrict__ Bt,
                  float* __restrict__ C)
{
    __shared__ __align__(16) short at[128 * 64];
    __shared__ __align__(16) short bt[128 * 64];
    const int tid  = threadIdx.x;
    const int lane = tid & 63;
    const int wid  = tid >> 6;
    const int wm = wid >> 1, wn = wid & 1;
    const int g = lane >> 4, l15 = lane & 15;
    const int wg = (blockIdx.x & 7) * 64 + (blockIdx.x >> 3);
    const int bn = wg & 15, bm = wg >> 4;
    const int m0 = bm * 128, n0 = bn * 128;

    float4v acc[4][4];
    #pragma unroll
    for (int mi = 0; mi < 4; ++mi)
        #pragma unroll
        for (int nj = 0; nj < 4; ++nj) acc[mi][nj] = (float4v){0.f, 0.f, 0.f, 0.f};

    for (int k0 = 0; k0 < 2048; k0 += 64) {
        __syncthreads();
        #pragma unroll
        for (int i = 0; i < 4; ++i) {
            int row = wid * 32 + i * 8 + (lane >> 3);
            int ch  = lane & 7;
            gl_lds16(A + (size_t)(m0 + row) * 2048 + k0 + ((ch ^ (row & 7)) * 8),
                     at + wid * 2048 + i * 512);
            gl_lds16(Bt + (size_t)(n0 + row) * 2048 + k0 + ((ch ^ (row & 7)) * 8),
                     bt + wid * 2048 + i * 512);
        }
        __syncthreads();

        #pragma unroll
        for (int kb = 0; kb < 2; ++kb) {
            short8 af[4], bfr[4];
            #pragma unroll
            for (int mi = 0; mi < 4; ++mi) {
                int row = wm * 64 + mi * 16 + l15;
                af[mi] = *reinterpret_cast<const short8*>(
                    at + row * 64 + (((g + 4 * kb) ^ (row & 7)) * 8));
            }
            #pragma unroll
            for (int nj = 0; nj < 4; ++nj) {
                int row = wn * 64 + nj * 16 + l15;
                bfr[nj] = *reinterpret_cast<const short8*>(
                    bt + row * 64 + (((g + 4 * kb) ^ (row & 7)) * 8));
            }
            #pragma unroll
            for (int mi = 0; mi < 4; ++mi)
                #pragma unroll
                for (int nj = 0; nj < 4; ++nj)
                    acc[mi][nj] = __builtin_amdgcn_mfma_f32_16x16x32_bf16(
                        af[mi], bfr[nj], acc[mi][nj], 0, 0, 0);
        }
    }

    #pragma unroll
    for (int mi = 0; mi < 4; ++mi)
        #pragma unroll
        for (int nj = 0; nj < 4; ++nj)
            #pragma unroll
            for (int r = 0; r < 4; ++r)
                C[(size_t)(m0 + wm * 64 + mi * 16 + g * 4 + r) * DIM + n0 + wn * 64 + nj * 16 + l15] =
                    acc[mi][nj][r];
}

// ---------------------------------------------------------------------------
extern "C" void kernel_launch(void* const* d_in, const int* in_sizes, int n_in,
                              void* d_out, int out_size, void* d_ws, size_t ws_size,
                              hipStream_t stream)
{
    const float* x        = (const float*)d_in[0];
    const float* w_dq     = (const float*)d_in[1];
    const float* gamma_q  = (const float*)d_in[2];
    const float* w_uq     = (const float*)d_in[3];
    const float* w_dkv    = (const float*)d_in[4];
    const float* gamma_kv = (const float*)d_in[5];
    const float* w_ukv    = (const float*)d_in[6];
    const float* w_o      = (const float*)d_in[7];
    float* out = (float*)d_out;

    char* ws = (char*)d_ws;
    float* tq       = (float*)(ws);                       // 0.25 MB
    float* tk       = (float*)(ws + (1ull  << 20));       // 0.5 MB
    short* w_uqT    = (short*)(ws + (2ull  << 20));       // 0.5 MB
    short* wdT      = (short*)(ws + (3ull  << 20));       // 1.25 MB
    short* WqcombT  = (short*)(ws + (5ull  << 20));       // 0.5 MB
    short* kimg     = (short*)(ws + (6ull  << 20));       // 1.5 MB
    short* vimg     = (short*)(ws + (8ull  << 20));       // 1 MB
    short* q_states = (short*)(ws + (10ull << 20));       // 25.2 MB
    short* attn_out = (short*)(ws + (36ull << 20));       // 16 MB
    short* WcombT   = (short*)(ws + (52ull << 20));       // 8 MB
    // total 60 MB

    kw_prep<<<dim3(880), dim3(256), 0, stream>>>(
        w_o, w_uq, w_ukv, w_dq, w_dkv, wdT, w_uqT, WqcombT, WcombT, tq, tk);

    k12_mfma<<<dim3(ROWS_TOT / 16), dim3(256), 0, stream>>>(
        x, wdT, gamma_q, gamma_kv, tk, tq, WqcombT, w_uqT, kimg, vimg, q_states);

    k4_attn_mfma<<<dim3(512), dim3(512), 0, stream>>>(
        q_states, kimg, vimg, attn_out);

    k5_gemm_mfma<<<dim3(512), dim3(256), 0, stream>>>(
        attn_out, WcombT, out);
}

// Round 14
// 240.432 us; speedup vs baseline: 1.0499x; 1.0499x over previous
//
#include <hip/hip_runtime.h>
#include <hip/hip_bf16.h>
#include <math.h>

#define DIM   2048
#define S_LEN 2048
#define BATCH 2
#define NH    16
#define NKV   4
#define CQ_   128
#define QN_   96
#define QR_   32
#define CKV_  128
#define KN_   64
#define KR_   64
#define VD_   256
#define DQK   192
#define DV    128
#define ROWS_TOT (BATCH*S_LEN)   // 4096
#define QK_SCALE 0.08838834764831845f
#define LOG2E    1.4426950408889634f

typedef __attribute__((ext_vector_type(8)))  short short8;
typedef __attribute__((ext_vector_type(4)))  short short4v;
typedef __attribute__((ext_vector_type(4)))  float float4v;
typedef __attribute__((ext_vector_type(16))) float float16v;
typedef __attribute__((ext_vector_type(4)))  int   int4v;

__device__ inline short f2bf(float x) {
    union { __hip_bfloat16 h; short s; } u;
    u.h = __float2bfloat16(x);
    return u.s;
}

__device__ __forceinline__ void gl_lds16(const short* g, short* lds) {
    __builtin_amdgcn_global_load_lds(
        (const __attribute__((address_space(1))) unsigned int*)(g),
        (__attribute__((address_space(3))) unsigned int*)(lds),
        16, 0, 0);
}

__device__ __forceinline__ short8 cast8(const float* p) {
    float4 a = *reinterpret_cast<const float4*>(p);
    float4 b = *reinterpret_cast<const float4*>(p + 4);
    short8 o;
    o[0] = f2bf(a.x); o[1] = f2bf(a.y); o[2] = f2bf(a.z); o[3] = f2bf(a.w);
    o[4] = f2bf(b.x); o[5] = f2bf(b.y); o[6] = f2bf(b.z); o[7] = f2bf(b.w);
    return o;
}

// ---------------------------------------------------------------------------
// KW: ALL weight prep in one launch (no w_oT intermediate).  [R13-proven]
//   [0,160): wdT   [160,224): w_uqT   [224,608): RoPE tables
//   [608,624): WqcombT   [624,880): WcombT (w_o staged via LDS transpose)
// ---------------------------------------------------------------------------
__global__ __launch_bounds__(256)
void kw_prep(const float* __restrict__ w_o, const float* __restrict__ w_uq,
             const float* __restrict__ w_ukv, const float* __restrict__ w_dq,
             const float* __restrict__ w_dkv,
             short* __restrict__ wdT, short* __restrict__ w_uqT,
             short* __restrict__ WqcombT, short* __restrict__ WcombT,
             float* __restrict__ tq, float* __restrict__ tk)
{
    __shared__ char smem[67584];
    const int bid = blockIdx.x, tid = threadIdx.x;
    const int lane = tid & 63, wid = tid >> 6;
    const int g = lane >> 4, l15 = lane & 15;

    if (bid < 224) {
        float* tf = (float*)smem;
        int lb, nct, R; short* dst;
        if (bid < 160) { lb = bid;       nct = 5;  R = 2048; dst = wdT;   }
        else           { lb = bid - 160; nct = 32; R = 128;  dst = w_uqT; }
        const int ct = lb % nct, rt = lb / nct;
        const int r0 = rt * 64, c0 = ct * 64;
        const float* src; int stride, nbase;
        if (bid < 160) {
            if (ct < 2) { src = w_dq;  stride = 128; nbase = c0; }
            else        { src = w_dkv; stride = 192; nbase = c0 - 128; }
        } else { src = w_uq; stride = 2048; nbase = c0; }

        #pragma unroll
        for (int u4 = 0; u4 < 4; ++u4) {
            int u = u4 * 256 + tid;
            int kr = u >> 4, nc = (u & 15) * 4;
            float4 v = *reinterpret_cast<const float4*>(&src[(size_t)(r0 + kr) * stride + nbase + nc]);
            tf[kr * 65 + nc + 0] = v.x; tf[kr * 65 + nc + 1] = v.y;
            tf[kr * 65 + nc + 2] = v.z; tf[kr * 65 + nc + 3] = v.w;
        }
        __syncthreads();
        #pragma unroll
        for (int u2 = 0; u2 < 2; ++u2) {
            int u = u2 * 256 + tid;
            int nr = u >> 3, kc8 = (u & 7) * 8;
            short8 o;
            #pragma unroll
            for (int j = 0; j < 8; ++j) o[j] = f2bf(tf[(kc8 + j) * 65 + nr]);
            *reinterpret_cast<short8*>(&dst[(size_t)(c0 + nr) * R + r0 + kc8]) = o;
        }
        return;
    }
    if (bid < 608) {
        int gid = (bid - 224) * 256 + tid;
        int spos = gid / 48, e = gid - spos * 48;
        if (e < 16) {
            float inv = powf(10000.f, -(float)(2 * e) / 32.f);
            float sn, c; sincosf((float)spos * inv, &sn, &c);
            tq[(spos * 16 + e) * 2 + 0] = c;
            tq[(spos * 16 + e) * 2 + 1] = sn;
        } else {
            int i2 = e - 16;
            float inv = powf(10000.f, -(float)(2 * i2) / 64.f);
            float sn, c; sincosf((float)spos * inv, &sn, &c);
            tk[(spos * 32 + i2) * 2 + 0] = c;
            tk[(spos * 32 + i2) * 2 + 1] = sn;
        }
        return;
    }
    if (bid < 624) {
        const int h = bid - 608, kvh = h >> 2;
        float4v acc[2][8];
        #pragma unroll
        for (int mi = 0; mi < 2; ++mi)
            #pragma unroll
            for (int nj = 0; nj < 8; ++nj) acc[mi][nj] = (float4v){0.f, 0.f, 0.f, 0.f};
        #pragma unroll
        for (int kb = 0; kb < 2; ++kb) {
            short8 af[2], bf[8];
            #pragma unroll
            for (int mi = 0; mi < 2; ++mi) {
                int j = wid * 32 + mi * 16 + l15;
                af[mi] = cast8(&w_ukv[(size_t)j * 1280 + kvh * 64 + kb * 32 + g * 8]);
            }
            #pragma unroll
            for (int nj = 0; nj < 8; ++nj) {
                int e = nj * 16 + l15;
                bf[nj] = cast8(&w_uq[(size_t)e * 2048 + h * 96 + kb * 32 + g * 8]);
            }
            #pragma unroll
            for (int mi = 0; mi < 2; ++mi)
                #pragma unroll
                for (int nj = 0; nj < 8; ++nj)
                    acc[mi][nj] = __builtin_amdgcn_mfma_f32_16x16x32_bf16(
                        af[mi], bf[nj], acc[mi][nj], 0, 0, 0);
        }
        #pragma unroll
        for (int mi = 0; mi < 2; ++mi)
            #pragma unroll
            for (int nj = 0; nj < 8; ++nj)
                #pragma unroll
                for (int r = 0; r < 4; ++r)
                    WqcombT[(size_t)h * 16384 + (wid * 32 + mi * 16 + g * 4 + r) * 128
                            + nj * 16 + l15] = f2bf(acc[mi][nj][r]);
        return;
    }

    {
        const int bb = bid - 624;
        const int h = bb >> 4, nt = bb & 15, kvh = h >> 2;
        const int wm = wid >> 1, wn = wid & 1;
        short* wot = (short*)smem;   // [128][264] bf16, padded

        for (int u = tid; u < 8192; u += 256) {
            int r = u >> 5, c4 = (u & 31) * 4;
            float4 v = *reinterpret_cast<const float4*>(
                &w_o[(size_t)(h * 256 + r) * DIM + nt * 128 + c4]);
            wot[(c4 + 0) * 264 + r] = f2bf(v.x);
            wot[(c4 + 1) * 264 + r] = f2bf(v.y);
            wot[(c4 + 2) * 264 + r] = f2bf(v.z);
            wot[(c4 + 3) * 264 + r] = f2bf(v.w);
        }
        __syncthreads();

        float4v acc[4][4];
        #pragma unroll
        for (int mi = 0; mi < 4; ++mi)
            #pragma unroll
            for (int nj = 0; nj < 4; ++nj) acc[mi][nj] = (float4v){0.f, 0.f, 0.f, 0.f};
        for (int kb = 0; kb < 8; ++kb) {
            short8 af[4], bf[4];
            #pragma unroll
            for (int mi = 0; mi < 4; ++mi) {
                int nl = wm * 64 + mi * 16 + l15;
                af[mi] = *reinterpret_cast<const short8*>(
                    &wot[nl * 264 + kb * 32 + g * 8]);
            }
            #pragma unroll
            for (int nj = 0; nj < 4; ++nj) {
                int c = wn * 64 + nj * 16 + l15;
                bf[nj] = cast8(&w_ukv[(size_t)c * 1280 + 256 + kvh * 256 + kb * 32 + g * 8]);
            }
            #pragma unroll
            for (int mi = 0; mi < 4; ++mi)
                #pragma unroll
                for (int nj = 0; nj < 4; ++nj)
                    acc[mi][nj] = __builtin_amdgcn_mfma_f32_16x16x32_bf16(
                        af[mi], bf[nj], acc[mi][nj], 0, 0, 0);
        }
        #pragma unroll
        for (int mi = 0; mi < 4; ++mi)
            #pragma unroll
            for (int nj = 0; nj < 4; ++nj)
                #pragma unroll
                for (int r = 0; r < 4; ++r)
                    WcombT[(size_t)(nt * 128 + wm * 64 + mi * 16 + g * 4 + r) * 2048
                           + h * 128 + wn * 64 + nj * 16 + l15] = f2bf(acc[mi][nj][r]);
    }
}

// ---------------------------------------------------------------------------
// K1: x @ [w_dq|w_dkv] (MFMA) + LN + K-RoPE -> cq_bf + kx images.  [R12]
// ---------------------------------------------------------------------------
__global__ __launch_bounds__(256)
void k1_mfma(const float* __restrict__ x, const short* __restrict__ wdT,
             const float* __restrict__ gamma_q, const float* __restrict__ gamma_kv,
             const float* __restrict__ tk,
             short* __restrict__ cq_bf, short* __restrict__ kimg,
             short* __restrict__ vimg)
{
    __shared__ float ys[16][321];
    __shared__ float st[16][4];
    const int tid = threadIdx.x, lane = tid & 63, w = tid >> 6;
    const int g = lane >> 4, l15 = lane & 15;
    const int m0 = blockIdx.x * 16;
    const int wn0 = w * 80;

    float4v acc[5];
    #pragma unroll
    for (int nj = 0; nj < 5; ++nj) acc[nj] = (float4v){0.f, 0.f, 0.f, 0.f};

    const float* arow = x + (size_t)(m0 + l15) * 2048 + g * 8;
    for (int ks = 0; ks < 64; ++ks) {
        short8 a = cast8(arow + ks * 32);
        #pragma unroll
        for (int nj = 0; nj < 5; ++nj) {
            short8 bf = *reinterpret_cast<const short8*>(
                wdT + (size_t)(wn0 + nj * 16 + l15) * 2048 + ks * 32 + g * 8);
            acc[nj] = __builtin_amdgcn_mfma_f32_16x16x32_bf16(a, bf, acc[nj], 0, 0, 0);
        }
    }

    #pragma unroll
    for (int nj = 0; nj < 5; ++nj)
        #pragma unroll
        for (int r = 0; r < 4; ++r)
            ys[g * 4 + r][wn0 + nj * 16 + l15] = acc[nj][r];
    __syncthreads();

    if (tid < 32) {
        int row = tid >> 1, seg = tid & 1, base = seg * 128;
        float s1 = 0.f, s2 = 0.f;
        for (int j = 0; j < 128; ++j) { float v = ys[row][base + j]; s1 += v; s2 += v * v; }
        float mu  = s1 * (1.f / 128.f);
        float var = s2 * (1.f / 128.f) - mu * mu;
        st[row][seg * 2 + 0] = mu;
        st[row][seg * 2 + 1] = rsqrtf(var + 1e-5f);
    }
    __syncthreads();

    for (int i = tid; i < 16 * 128; i += 256) {
        int row = i >> 7, col = i & 127;
        int r = m0 + row;
        cq_bf[(size_t)r * CQ_ + col] =
            f2bf((ys[row][col] - st[row][0]) * st[row][1] * gamma_q[col] * (QK_SCALE * LOG2E));
    }
    for (int i = tid; i < 16 * 192; i += 256) {
        int row = i / 192, d = i - row * 192;
        int r = m0 + row, b = r >> 11, spos = r & (S_LEN - 1);
        int tile = b * 32 + (spos >> 6);
        if (d < 128) {
            float val = (ys[row][128 + d] - st[row][2]) * st[row][3] * gamma_kv[d];
            short v_ = f2bf(val);
            size_t vslot = (d >> 5) * 256 + ((spos >> 5) & 1) * 128
                           + ((spos >> 4) & 1) * 64 + ((spos >> 3) & 1) * 32 + (d & 31);
            vimg[((size_t)tile * 1024 + vslot) * 8 + (spos & 7)] = v_;
            size_t kslot = ((spos >> 5) & 1) * 768 + (d >> 4) * 64
                           + ((d >> 3) & 1) * 32 + (spos & 31);
            kimg[((size_t)tile * 1536 + kslot) * 8 + (d & 7)] = v_;
        } else {
            int dd = d - 128, i2 = dd >> 1;
            float xe = ys[row][256 + (dd & ~1)];
            float xo = ys[row][256 + (dd | 1)];
            float c  = tk[(spos * 32 + i2) * 2 + 0];
            float sn = tk[(spos * 32 + i2) * 2 + 1];
            float val = (dd & 1) ? (xe * sn + xo * c) : (xe * c - xo * sn);
            size_t kslot = ((spos >> 5) & 1) * 768 + (d >> 4) * 64
                           + ((d >> 3) & 1) * 32 + (spos & 31);
            kimg[((size_t)tile * 1536 + kslot) * 8 + (d & 7)] = f2bf(val);
        }
    }
}

// ---------------------------------------------------------------------------
// K2: q~ = cq_bf @ [WqcombT | w_uq slices] + Q-RoPE -> q_states (B,H,S,192)
//   [R12] grid: 256 m-tiles x 3 col-chunks = 768 blocks.
// ---------------------------------------------------------------------------
__global__ __launch_bounds__(256)
void k2_mfma(const short* __restrict__ cq_bf, const short* __restrict__ WqcombT,
             const short* __restrict__ w_uqT, const float* __restrict__ tq,
             short* __restrict__ q_states)
{
    const int tid = threadIdx.x, lane = tid & 63, w = tid >> 6;
    const int g = lane >> 4, l15 = lane & 15;
    const int bm = blockIdx.x / 3, ns = blockIdx.x % 3;
    const int m0 = bm * 16;
    const int nb = ns * 1024 + w * 256;

    short8 af[4];
    #pragma unroll
    for (int ks = 0; ks < 4; ++ks)
        af[ks] = *reinterpret_cast<const short8*>(
            cq_bf + (size_t)(m0 + l15) * 128 + ks * 32 + g * 8);

    float4v acc[16];
    #pragma unroll
    for (int nj = 0; nj < 16; ++nj) acc[nj] = (float4v){0.f, 0.f, 0.f, 0.f};

    #pragma unroll
    for (int ks = 0; ks < 4; ++ks)
        #pragma unroll
        for (int nj = 0; nj < 16; ++nj) {
            int j = nb + nj * 16 + l15;
            int h = j / 192, t = j - h * 192;
            const short* brow;
            if (t < 128)       brow = WqcombT + (size_t)h * 16384 + (size_t)t * 128;
            else if (t < 160)  brow = w_uqT + (size_t)(h * 96 + 64 + (t - 128)) * 128;
            else               brow = w_uqT + (size_t)(1536 + h * 32 + (t - 160)) * 128;
            short8 bf = *reinterpret_cast<const short8*>(brow + ks * 32 + g * 8);
            acc[nj] = __builtin_amdgcn_mfma_f32_16x16x32_bf16(af[ks], bf, acc[nj], 0, 0, 0);
        }

    #pragma unroll
    for (int nj = 0; nj < 16; ++nj) {
        int j = nb + nj * 16 + l15;
        int h = j / 192, t = j - h * 192;
        if (t < 160) {
            #pragma unroll
            for (int r = 0; r < 4; ++r) {
                int rg = m0 + g * 4 + r, bb = rg >> 11, spos = rg & (S_LEN - 1);
                q_states[((size_t)(bb * NH + h) * S_LEN + spos) * DQK + t] =
                    f2bf(acc[nj][r]);
            }
        } else {
            int dd = t - 160, i2 = dd >> 1;
            #pragma unroll
            for (int r = 0; r < 4; ++r) {
                int rg = m0 + g * 4 + r, bb = rg >> 11, spos = rg & (S_LEN - 1);
                float v = acc[nj][r];
                float p = __shfl_xor(v, 1, 64);
                float c  = tq[(spos * 16 + i2) * 2 + 0];
                float sn = tq[(spos * 16 + i2) * 2 + 1];
                float out = (dd & 1) ? (p * sn + v * c) : (v * c - p * sn);
                q_states[((size_t)(bb * NH + h) * S_LEN + spos) * DQK + t] = f2bf(out);
            }
        }
    }
}

// ---------------------------------------------------------------------------
// K4: absorbed-MLA swapped-QK 32x32 MFMA flash attention (R12-proven, verbatim).
// ---------------------------------------------------------------------------
__global__ __launch_bounds__(512, 1)
void k4_attn_mfma(const short* __restrict__ q_states,
                  const short* __restrict__ kimg,
                  const short* __restrict__ vimg,
                  short* __restrict__ attn_out)
{
    __shared__ __align__(16) short ks_lds[3][12288];   // 3 x 24 KB
    __shared__ __align__(16) short vt_lds[2][8192];    // 2 x 16 KB

    const int tid = threadIdx.x, lane = tid & 63, w = tid >> 6;
    const int bid = blockIdx.x;
    const int l31 = lane & 31, hi = lane >> 5;
    const int g = w & 3, h = w >> 2;
    const int qt = (bid < 256) ? (15 - (bid >> 5)) : (7 - ((bid - 256) >> 5));
    const int bh = bid & 31;
    const int h_head = bh & 15, b = bh >> 4;

    const short* kfbase = kimg + (size_t)b * 32 * 12288;
    const short* vfbase = vimg + (size_t)b * 32 * 8192;

    const int qrow0 = qt * 128 + g * 32;
    const int qglob = qrow0 + l31;

    short8 qcur[12];
    {
        const short* qr = q_states +
            ((size_t)(b * NH + h_head) * S_LEN + qglob) * DQK + hi * 8;
        #pragma unroll
        for (int st = 0; st < 12; ++st)
            qcur[st] = *reinterpret_cast<const short8*>(qr + st * 16);
    }

    float16v o[4];
    #pragma unroll
    for (int dt = 0; dt < 4; ++dt)
        #pragma unroll
        for (int r = 0; r < 16; ++r) o[dt][r] = 0.f;
    float mreg = -1e30f, lreg = 0.f;

    const int nkt = 2 * (qt + 1);

    auto issueK = [&](int kt, int bufi) {
        const short* src = kfbase + (size_t)kt * 12288;
        #pragma unroll
        for (int i = 0; i < 3; ++i) {
            int c = w * 3 + i;
            gl_lds16(src + c * 512 + lane * 8, &ks_lds[bufi][c * 512]);
        }
    };
    auto issueV = [&](int kt, int bufi) {
        const short* src = vfbase + (size_t)kt * 8192;
        #pragma unroll
        for (int i = 0; i < 2; ++i) {
            int c = w * 2 + i;
            gl_lds16(src + c * 512 + lane * 8, &vt_lds[bufi][c * 512]);
        }
    };

    issueK(0, 0);
    issueV(0, 0);
    issueK(1, 1);

    for (int seq = 0; seq < nkt; ++seq) {
        if (seq < nkt - 1) { asm volatile("s_waitcnt vmcnt(3)" ::: "memory"); }
        else               { asm volatile("s_waitcnt vmcnt(0)" ::: "memory"); }
        __builtin_amdgcn_s_barrier();
        __builtin_amdgcn_sched_barrier(0);

        if (seq + 1 < nkt) issueV(seq + 1, (seq + 1) & 1);
        if (seq + 2 < nkt) issueK(seq + 2, (seq + 2) % 3);

        const int kvb = seq * 64 + h * 32;
        if (kvb <= qrow0 + 31) {
            const short* kbuf = &ks_lds[seq % 3][h * 6144];
            float16v sa, sb;
            #pragma unroll
            for (int r = 0; r < 16; ++r) { sa[r] = 0.f; sb[r] = 0.f; }
            __builtin_amdgcn_s_setprio(1);
            #pragma unroll
            for (int st = 0; st < 12; st += 2) {
                short8 kf0 = *reinterpret_cast<const short8*>(kbuf + st * 512 + lane * 8);
                sa = __builtin_amdgcn_mfma_f32_32x32x16_bf16(kf0, qcur[st], sa, 0, 0, 0);
                short8 kf1 = *reinterpret_cast<const short8*>(kbuf + (st + 1) * 512 + lane * 8);
                sb = __builtin_amdgcn_mfma_f32_32x32x16_bf16(kf1, qcur[st + 1], sb, 0, 0, 0);
            }
            __builtin_amdgcn_s_setprio(0);
            float16v s;
            #pragma unroll
            for (int r = 0; r < 16; ++r) s[r] = sa[r] + sb[r];

            if (kvb + 31 > qrow0) {
                #pragma unroll
                for (int r = 0; r < 16; ++r) {
                    int kc = kvb + ((r & 3) + 8 * (r >> 2) + 4 * hi);
                    if (kc > qglob) s[r] = -1e30f;
                }
            }

            float mx = s[0];
            #pragma unroll
            for (int r = 1; r < 16; ++r) mx = fmaxf(mx, s[r]);
            mx = fmaxf(mx, __shfl_xor(mx, 32, 64));
            bool need = mx > mreg + 8.f;
            if (__ballot(need)) {
                float mnew = fmaxf(mreg, mx);
                float corr = exp2f(mreg - mnew);
                mreg = mnew;
                lreg *= corr;
                #pragma unroll
                for (int dt = 0; dt < 4; ++dt)
                    #pragma unroll
                    for (int r = 0; r < 16; ++r) o[dt][r] *= corr;
            }
            #pragma unroll
            for (int r = 0; r < 16; ++r) s[r] = exp2f(s[r] - mreg);
            float ps = 0.f;
            #pragma unroll
            for (int r = 0; r < 16; ++r) ps += s[r];
            ps += __shfl_xor(ps, 32, 64);
            lreg += ps;

            const short* vbuf = &vt_lds[seq & 1][h * 1024];
            __builtin_amdgcn_s_setprio(1);
            #pragma unroll
            for (int ks = 0; ks < 2; ++ks) {
                const int rb = ks * 8;
                int c01, c23, c45, c67;
                asm("v_cvt_pk_bf16_f32 %0, %1, %2" : "=v"(c01) : "v"(s[rb+0]), "v"(s[rb+1]));
                asm("v_cvt_pk_bf16_f32 %0, %1, %2" : "=v"(c23) : "v"(s[rb+2]), "v"(s[rb+3]));
                asm("v_cvt_pk_bf16_f32 %0, %1, %2" : "=v"(c45) : "v"(s[rb+4]), "v"(s[rb+5]));
                asm("v_cvt_pk_bf16_f32 %0, %1, %2" : "=v"(c67) : "v"(s[rb+6]), "v"(s[rb+7]));
                asm("v_permlane32_swap_b32 %0, %1" : "+v"(c01), "+v"(c45));
                asm("v_permlane32_swap_b32 %0, %1" : "+v"(c23), "+v"(c67));
                union { int4v i4; short8 s8; } u_;
                u_.i4.x = c01; u_.i4.y = c23; u_.i4.z = c45; u_.i4.w = c67;
                short8 pa = u_.s8;
                #pragma unroll
                for (int dt = 0; dt < 4; ++dt) {
                    short8 vf = *reinterpret_cast<const short8*>(
                        vbuf + dt * 2048 + ks * 512 + lane * 8);
                    o[dt] = __builtin_amdgcn_mfma_f32_32x32x16_bf16(vf, pa, o[dt], 0, 0, 0);
                }
            }
            __builtin_amdgcn_s_setprio(0);
        }
    }

    __syncthreads();
    {
        float* mlb = (float*)(&ks_lds[0][0]);
        mlb[w * 64 + lane] = mreg;
        mlb[512 + w * 64 + lane] = lreg;
    }
    __syncthreads();
    float s0f = 0.f, s1f = 0.f;
    if (h == 0) {
        float* mlb = (float*)(&ks_lds[0][0]);
        float m1 = mlb[(w + 4) * 64 + lane];
        float l1 = mlb[512 + (w + 4) * 64 + lane];
        float ms = fmaxf(mreg, m1);
        float c0 = exp2f(mreg - ms), c1 = exp2f(m1 - ms);
        float ls = lreg * c0 + l1 * c1;
        s0f = c0 / ls; s1f = c1 / ls;
    }
    float* cb = (float*)(&ks_lds[0][0]) + 1024;
    short* obase = attn_out + ((size_t)(b * S_LEN + qglob)) * 2048 + h_head * 128;
    for (int dt = 0; dt < 4; ++dt) {
        __syncthreads();
        if (h == 1) {
            #pragma unroll
            for (int r = 0; r < 16; ++r)
                cb[r * 256 + g * 64 + lane] = o[dt][r];
        }
        __syncthreads();
        if (h == 0) {
            #pragma unroll
            for (int r = 0; r < 16; ++r)
                o[dt][r] = o[dt][r] * s0f + cb[r * 256 + g * 64 + lane] * s1f;
            #pragma unroll
            for (int k4i = 0; k4i < 4; ++k4i) {
                int d0 = dt * 32 + k4i * 8 + hi * 4;
                short4v pk;
                #pragma unroll
                for (int j = 0; j < 4; ++j) pk[j] = f2bf(o[dt][k4i * 4 + j]);
                *reinterpret_cast<short4v*>(obase + d0) = pk;
            }
        }
    }
}

// ---------------------------------------------------------------------------
// K5: out = attn_out (4096x2048 bf16) @ WcombT (2048x2048 bf16), f32 out.
// ---------------------------------------------------------------------------
__global__ __launch_bounds__(256)
void k5_gemm_mfma(const short* __restrict__ A,
                  const short* __restrict__ Bt,
                  float* __restrict__ C)
{
    __shared__ __align__(16) short at[128 * 64];
    __shared__ __align__(16) short bt[128 * 64];
    const int tid  = threadIdx.x;
    const int lane = tid & 63;
    const int wid  = tid >> 6;
    const int wm = wid >> 1, wn = wid & 1;
    const int g = lane >> 4, l15 = lane & 15;
    const int wg = (blockIdx.x & 7) * 64 + (blockIdx.x >> 3);
    const int bn = wg & 15, bm = wg >> 4;
    const int m0 = bm * 128, n0 = bn * 128;

    float4v acc[4][4];
    #pragma unroll
    for (int mi = 0; mi < 4; ++mi)
        #pragma unroll
        for (int nj = 0; nj < 4; ++nj) acc[mi][nj] = (float4v){0.f, 0.f, 0.f, 0.f};

    for (int k0 = 0; k0 < 2048; k0 += 64) {
        __syncthreads();
        #pragma unroll
        for (int i = 0; i < 4; ++i) {
            int row = wid * 32 + i * 8 + (lane >> 3);
            int ch  = lane & 7;
            gl_lds16(A + (size_t)(m0 + row) * 2048 + k0 + ((ch ^ (row & 7)) * 8),
                     at + wid * 2048 + i * 512);
            gl_lds16(Bt + (size_t)(n0 + row) * 2048 + k0 + ((ch ^ (row & 7)) * 8),
                     bt + wid * 2048 + i * 512);
        }
        __syncthreads();

        #pragma unroll
        for (int kb = 0; kb < 2; ++kb) {
            short8 af[4], bfr[4];
            #pragma unroll
            for (int mi = 0; mi < 4; ++mi) {
                int row = wm * 64 + mi * 16 + l15;
                af[mi] = *reinterpret_cast<const short8*>(
                    at + row * 64 + (((g + 4 * kb) ^ (row & 7)) * 8));
            }
            #pragma unroll
            for (int nj = 0; nj < 4; ++nj) {
                int row = wn * 64 + nj * 16 + l15;
                bfr[nj] = *reinterpret_cast<const short8*>(
                    bt + row * 64 + (((g + 4 * kb) ^ (row & 7)) * 8));
            }
            #pragma unroll
            for (int mi = 0; mi < 4; ++mi)
                #pragma unroll
                for (int nj = 0; nj < 4; ++nj)
                    acc[mi][nj] = __builtin_amdgcn_mfma_f32_16x16x32_bf16(
                        af[mi], bfr[nj], acc[mi][nj], 0, 0, 0);
        }
    }

    #pragma unroll
    for (int mi = 0; mi < 4; ++mi)
        #pragma unroll
        for (int nj = 0; nj < 4; ++nj)
            #pragma unroll
            for (int r = 0; r < 4; ++r)
                C[(size_t)(m0 + wm * 64 + mi * 16 + g * 4 + r) * DIM + n0 + wn * 64 + nj * 16 + l15] =
                    acc[mi][nj][r];
}

// ---------------------------------------------------------------------------
extern "C" void kernel_launch(void* const* d_in, const int* in_sizes, int n_in,
                              void* d_out, int out_size, void* d_ws, size_t ws_size,
                              hipStream_t stream)
{
    const float* x        = (const float*)d_in[0];
    const float* w_dq     = (const float*)d_in[1];
    const float* gamma_q  = (const float*)d_in[2];
    const float* w_uq     = (const float*)d_in[3];
    const float* w_dkv    = (const float*)d_in[4];
    const float* gamma_kv = (const float*)d_in[5];
    const float* w_ukv    = (const float*)d_in[6];
    const float* w_o      = (const float*)d_in[7];
    float* out = (float*)d_out;

    char* ws = (char*)d_ws;
    float* tq       = (float*)(ws);                       // 0.25 MB
    float* tk       = (float*)(ws + (1ull  << 20));       // 0.5 MB
    short* w_uqT    = (short*)(ws + (2ull  << 20));       // 0.5 MB
    short* wdT      = (short*)(ws + (3ull  << 20));       // 1.25 MB
    short* WqcombT  = (short*)(ws + (5ull  << 20));       // 0.5 MB
    short* kimg     = (short*)(ws + (6ull  << 20));       // 1.5 MB
    short* vimg     = (short*)(ws + (8ull  << 20));       // 1 MB
    short* cq_bf    = (short*)(ws + (9ull  << 20));       // 1 MB
    short* q_states = (short*)(ws + (10ull << 20));       // 25.2 MB
    short* attn_out = (short*)(ws + (36ull << 20));       // 16 MB
    short* WcombT   = (short*)(ws + (52ull << 20));       // 8 MB
    // total 60 MB

    kw_prep<<<dim3(880), dim3(256), 0, stream>>>(
        w_o, w_uq, w_ukv, w_dq, w_dkv, wdT, w_uqT, WqcombT, WcombT, tq, tk);

    k1_mfma<<<dim3(ROWS_TOT / 16), dim3(256), 0, stream>>>(
        x, wdT, gamma_q, gamma_kv, tk, cq_bf, kimg, vimg);

    k2_mfma<<<dim3((ROWS_TOT / 16) * 3), dim3(256), 0, stream>>>(
        cq_bf, WqcombT, w_uqT, tq, q_states);

    k4_attn_mfma<<<dim3(512), dim3(512), 0, stream>>>(
        q_states, kimg, vimg, attn_out);

    k5_gemm_mfma<<<dim3(512), dim3(256), 0, stream>>>(
        attn_out, WcombT, out);
}

// Round 15
// 236.038 us; speedup vs baseline: 1.0695x; 1.0186x over previous
//
#include <hip/hip_runtime.h>
#include <hip/hip_bf16.h>
#include <math.h>

#define DIM   2048
#define S_LEN 2048
#define BATCH 2
#define NH    16
#define NKV   4
#define CQ_   128
#define QN_   96
#define QR_   32
#define CKV_  128
#define KN_   64
#define KR_   64
#define VD_   256
#define DQK   192          // absorbed: 128 (ckv) + 64 (k_rope)
#define DV    128          // absorbed: O'' = P @ ckv
#define ROWS_TOT (BATCH*S_LEN)   // 4096
#define QK_SCALE 0.08838834764831845f
#define LOG2E    1.4426950408889634f

typedef __attribute__((ext_vector_type(8)))  short short8;
typedef __attribute__((ext_vector_type(4)))  short short4v;
typedef __attribute__((ext_vector_type(4)))  float float4v;
typedef __attribute__((ext_vector_type(16))) float float16v;
typedef __attribute__((ext_vector_type(4)))  int   int4v;

__device__ inline short f2bf(float x) {
    union { __hip_bfloat16 h; short s; } u;
    u.h = __float2bfloat16(x);
    return u.s;
}

// async global->LDS, 16B/lane; LDS dest wave-uniform base (HW: base+lane*16).
__device__ __forceinline__ void gl_lds16(const short* g, short* lds) {
    __builtin_amdgcn_global_load_lds(
        (const __attribute__((address_space(1))) unsigned int*)(g),
        (__attribute__((address_space(3))) unsigned int*)(lds),
        16, 0, 0);
}

__device__ __forceinline__ short8 cast8(const float* p) {
    float4 a = *reinterpret_cast<const float4*>(p);
    float4 b = *reinterpret_cast<const float4*>(p + 4);
    short8 o;
    o[0] = f2bf(a.x); o[1] = f2bf(a.y); o[2] = f2bf(a.z); o[3] = f2bf(a.w);
    o[4] = f2bf(b.x); o[5] = f2bf(b.y); o[6] = f2bf(b.z); o[7] = f2bf(b.w);
    return o;
}

// Fragment-major images of kx = [ckv_ln(128) ; kr_rope(64)] per token:
// kimg (QK A-operand): tile = b*32 + (spos>>6)  (1536 slots = 24KB)
//   slot = ((spos>>5)&1)*768 + (d>>4)*64 + ((d>>3)&1)*32 + (spos&31); elem=d&7
// vimg (PV A-operand, d<128): tile = b*32 + (spos>>6)  (1024 slots = 16KB)
//   slot = (d>>5)*256 + ((spos>>5)&1)*128 + ((spos>>4)&1)*64
//          + ((spos>>3)&1)*32 + (d&31); elem = spos&7

// ---------------------------------------------------------------------------
// KPREP: weight transposes (f32 -> bf16^T) + RoPE tables.
//   [0,160): [w_dq|w_dkv] -> wdT   [160,224): w_uq -> w_uqT
//   [224,2272): w_o -> w_oT        [2272,2656): RoPE tables
// ---------------------------------------------------------------------------
__global__ __launch_bounds__(256)
void kprep_all(const float* __restrict__ w_o, const float* __restrict__ w_uq,
               const float* __restrict__ w_dq, const float* __restrict__ w_dkv,
               short* __restrict__ w_oT, short* __restrict__ w_uqT,
               short* __restrict__ wdT, float* __restrict__ tq,
               float* __restrict__ tk)
{
    const int bid = blockIdx.x, tid = threadIdx.x;
    if (bid >= 2272) {   // RoPE tables: 384*256 = 2048*48 slots
        int gid = (bid - 2272) * 256 + tid;
        int spos = gid / 48, e = gid - spos * 48;
        if (e < 16) {
            float inv = powf(10000.f, -(float)(2 * e) / 32.f);
            float sn, c; sincosf((float)spos * inv, &sn, &c);
            tq[(spos * 16 + e) * 2 + 0] = c;
            tq[(spos * 16 + e) * 2 + 1] = sn;
        } else {
            int i2 = e - 16;
            float inv = powf(10000.f, -(float)(2 * i2) / 64.f);
            float sn, c; sincosf((float)spos * inv, &sn, &c);
            tk[(spos * 32 + i2) * 2 + 0] = c;
            tk[(spos * 32 + i2) * 2 + 1] = sn;
        }
        return;
    }

    __shared__ float tf[64][65];
    int lb, nct, R; short* dst;
    if (bid < 160)      { lb = bid;       nct = 5;  R = 2048; dst = wdT;   }
    else if (bid < 224) { lb = bid - 160; nct = 32; R = 128;  dst = w_uqT; }
    else                { lb = bid - 224; nct = 32; R = 4096; dst = w_oT;  }
    const int ct = lb % nct, rt = lb / nct;
    const int r0 = rt * 64, c0 = ct * 64;
    const float* src; int stride, nbase;
    if (bid < 160) {
        if (ct < 2) { src = w_dq;  stride = 128; nbase = c0; }
        else        { src = w_dkv; stride = 192; nbase = c0 - 128; }
    } else if (bid < 224) { src = w_uq; stride = 2048; nbase = c0; }
    else                  { src = w_o;  stride = 2048; nbase = c0; }

    #pragma unroll
    for (int u4 = 0; u4 < 4; ++u4) {
        int u = u4 * 256 + tid;
        int kr = u >> 4, nc = (u & 15) * 4;
        float4 v = *reinterpret_cast<const float4*>(&src[(size_t)(r0 + kr) * stride + nbase + nc]);
        tf[kr][nc + 0] = v.x; tf[kr][nc + 1] = v.y;
        tf[kr][nc + 2] = v.z; tf[kr][nc + 3] = v.w;
    }
    __syncthreads();
    #pragma unroll
    for (int u2 = 0; u2 < 2; ++u2) {
        int u = u2 * 256 + tid;
        int nr = u >> 3, kc8 = (u & 7) * 8;
        short8 o;
        #pragma unroll
        for (int j = 0; j < 8; ++j) o[j] = f2bf(tf[kc8 + j][nr]);
        *reinterpret_cast<short8*>(&dst[(size_t)(c0 + nr) * R + r0 + kc8]) = o;
    }
}

// ---------------------------------------------------------------------------
// KCOMB: absorbed-weight precombines (after kprep).
//   bid<16 : WqcombT[h][c,e] = sum_d w_ukv[c, kvh*64+d] * w_uq[e, h*96+d]
//   else   : WcombT[n, h*128+c] = sum_d w_ukv[c, 256+kvh*256+d] * w_oT[n, h*256+d]
// ---------------------------------------------------------------------------
__global__ __launch_bounds__(256)
void kcomb(const float* __restrict__ w_uq, const float* __restrict__ w_ukv,
           const short* __restrict__ w_oT,
           short* __restrict__ WqcombT, short* __restrict__ WcombT)
{
    const int tid = threadIdx.x, lane = tid & 63, wid = tid >> 6;
    const int g = lane >> 4, l15 = lane & 15;

    if (blockIdx.x < 16) {
        const int h = blockIdx.x, kvh = h >> 2;
        float4v acc[2][8];
        #pragma unroll
        for (int mi = 0; mi < 2; ++mi)
            #pragma unroll
            for (int nj = 0; nj < 8; ++nj) acc[mi][nj] = (float4v){0.f, 0.f, 0.f, 0.f};
        #pragma unroll
        for (int kb = 0; kb < 2; ++kb) {
            short8 af[2], bf[8];
            #pragma unroll
            for (int mi = 0; mi < 2; ++mi) {
                int j = wid * 32 + mi * 16 + l15;   // c row
                af[mi] = cast8(&w_ukv[(size_t)j * 1280 + kvh * 64 + kb * 32 + g * 8]);
            }
            #pragma unroll
            for (int nj = 0; nj < 8; ++nj) {
                int e = nj * 16 + l15;
                bf[nj] = cast8(&w_uq[(size_t)e * 2048 + h * 96 + kb * 32 + g * 8]);
            }
            #pragma unroll
            for (int mi = 0; mi < 2; ++mi)
                #pragma unroll
                for (int nj = 0; nj < 8; ++nj)
                    acc[mi][nj] = __builtin_amdgcn_mfma_f32_16x16x32_bf16(
                        af[mi], bf[nj], acc[mi][nj], 0, 0, 0);
        }
        #pragma unroll
        for (int mi = 0; mi < 2; ++mi)
            #pragma unroll
            for (int nj = 0; nj < 8; ++nj)
                #pragma unroll
                for (int r = 0; r < 4; ++r)
                    WqcombT[(size_t)h * 16384 + (wid * 32 + mi * 16 + g * 4 + r) * 128
                            + nj * 16 + l15] = f2bf(acc[mi][nj][r]);
    } else {
        const int bb = blockIdx.x - 16;
        const int h = bb >> 4, nt = bb & 15, kvh = h >> 2;
        const int wm = wid >> 1, wn = wid & 1;
        float4v acc[4][4];
        #pragma unroll
        for (int mi = 0; mi < 4; ++mi)
            #pragma unroll
            for (int nj = 0; nj < 4; ++nj) acc[mi][nj] = (float4v){0.f, 0.f, 0.f, 0.f};
        for (int kb = 0; kb < 8; ++kb) {
            short8 af[4], bf[4];
            #pragma unroll
            for (int mi = 0; mi < 4; ++mi) {
                int n = nt * 128 + wm * 64 + mi * 16 + l15;
                af[mi] = *reinterpret_cast<const short8*>(
                    &w_oT[(size_t)n * 4096 + h * 256 + kb * 32 + g * 8]);
            }
            #pragma unroll
            for (int nj = 0; nj < 4; ++nj) {
                int c = wn * 64 + nj * 16 + l15;
                bf[nj] = cast8(&w_ukv[(size_t)c * 1280 + 256 + kvh * 256 + kb * 32 + g * 8]);
            }
            #pragma unroll
            for (int mi = 0; mi < 4; ++mi)
                #pragma unroll
                for (int nj = 0; nj < 4; ++nj)
                    acc[mi][nj] = __builtin_amdgcn_mfma_f32_16x16x32_bf16(
                        af[mi], bf[nj], acc[mi][nj], 0, 0, 0);
        }
        #pragma unroll
        for (int mi = 0; mi < 4; ++mi)
            #pragma unroll
            for (int nj = 0; nj < 4; ++nj)
                #pragma unroll
                for (int r = 0; r < 4; ++r)
                    WcombT[(size_t)(nt * 128 + wm * 64 + mi * 16 + g * 4 + r) * 2048
                           + h * 128 + wn * 64 + nj * 16 + l15] = f2bf(acc[mi][nj][r]);
    }
}

// ---------------------------------------------------------------------------
// K1: x @ [w_dq|w_dkv] (MFMA) + LN + K-RoPE -> cq_bf (scaled) and the
//   fragment-major kx images (kimg 192-dim, vimg 128-dim). f32 x direct.
// ---------------------------------------------------------------------------
__global__ __launch_bounds__(256)
void k1_mfma(const float* __restrict__ x, const short* __restrict__ wdT,
             const float* __restrict__ gamma_q, const float* __restrict__ gamma_kv,
             const float* __restrict__ tk,
             short* __restrict__ cq_bf, short* __restrict__ kimg,
             short* __restrict__ vimg)
{
    __shared__ float ys[16][321];
    __shared__ float st[16][4];
    const int tid = threadIdx.x, lane = tid & 63, w = tid >> 6;
    const int g = lane >> 4, l15 = lane & 15;
    const int m0 = blockIdx.x * 16;
    const int wn0 = w * 80;

    float4v acc[5];
    #pragma unroll
    for (int nj = 0; nj < 5; ++nj) acc[nj] = (float4v){0.f, 0.f, 0.f, 0.f};

    const float* arow = x + (size_t)(m0 + l15) * 2048 + g * 8;
    for (int ks = 0; ks < 64; ++ks) {
        short8 a = cast8(arow + ks * 32);
        #pragma unroll
        for (int nj = 0; nj < 5; ++nj) {
            short8 bf = *reinterpret_cast<const short8*>(
                wdT + (size_t)(wn0 + nj * 16 + l15) * 2048 + ks * 32 + g * 8);
            acc[nj] = __builtin_amdgcn_mfma_f32_16x16x32_bf16(a, bf, acc[nj], 0, 0, 0);
        }
    }

    #pragma unroll
    for (int nj = 0; nj < 5; ++nj)
        #pragma unroll
        for (int r = 0; r < 4; ++r)
            ys[g * 4 + r][wn0 + nj * 16 + l15] = acc[nj][r];
    __syncthreads();

    if (tid < 32) {
        int row = tid >> 1, seg = tid & 1, base = seg * 128;
        float s1 = 0.f, s2 = 0.f;
        for (int j = 0; j < 128; ++j) { float v = ys[row][base + j]; s1 += v; s2 += v * v; }
        float mu  = s1 * (1.f / 128.f);
        float var = s2 * (1.f / 128.f) - mu * mu;
        st[row][seg * 2 + 0] = mu;
        st[row][seg * 2 + 1] = rsqrtf(var + 1e-5f);
    }
    __syncthreads();

    // cq (scaled)
    for (int i = tid; i < 16 * 128; i += 256) {
        int row = i >> 7, col = i & 127;
        int r = m0 + row;
        cq_bf[(size_t)r * CQ_ + col] =
            f2bf((ys[row][col] - st[row][0]) * st[row][1] * gamma_q[col] * (QK_SCALE * LOG2E));
    }
    // kx images: d<128 = LN(ckv) -> kimg+vimg; d in [128,192) = rope -> kimg
    for (int i = tid; i < 16 * 192; i += 256) {
        int row = i / 192, d = i - row * 192;
        int r = m0 + row, b = r >> 11, spos = r & (S_LEN - 1);
        int tile = b * 32 + (spos >> 6);
        float val;
        if (d < 128) {
            val = (ys[row][128 + d] - st[row][2]) * st[row][3] * gamma_kv[d];
            short v_ = f2bf(val);
            size_t vslot = (d >> 5) * 256 + ((spos >> 5) & 1) * 128
                           + ((spos >> 4) & 1) * 64 + ((spos >> 3) & 1) * 32 + (d & 31);
            vimg[((size_t)tile * 1024 + vslot) * 8 + (spos & 7)] = v_;
            size_t kslot = ((spos >> 5) & 1) * 768 + (d >> 4) * 64
                           + ((d >> 3) & 1) * 32 + (spos & 31);
            kimg[((size_t)tile * 1536 + kslot) * 8 + (d & 7)] = v_;
        } else {
            int dd = d - 128, i2 = dd >> 1;
            float xe = ys[row][256 + (dd & ~1)];
            float xo = ys[row][256 + (dd | 1)];
            float c  = tk[(spos * 32 + i2) * 2 + 0];
            float sn = tk[(spos * 32 + i2) * 2 + 1];
            val = (dd & 1) ? (xe * sn + xo * c) : (xe * c - xo * sn);
            size_t kslot = ((spos >> 5) & 1) * 768 + (d >> 4) * 64
                           + ((d >> 3) & 1) * 32 + (spos & 31);
            kimg[((size_t)tile * 1536 + kslot) * 8 + (d & 7)] = f2bf(val);
        }
    }
}

// ---------------------------------------------------------------------------
// K2: q~ = cq_bf @ [WqcombT | w_uq slices] + Q-RoPE -> q_states (B,H,S,192)
//   grid: 256 m-tiles x 3 col-chunks (1024 cols each of 3072 = 16 heads x 192)
// ---------------------------------------------------------------------------
__global__ __launch_bounds__(256)
void k2_mfma(const short* __restrict__ cq_bf, const short* __restrict__ WqcombT,
             const short* __restrict__ w_uqT, const float* __restrict__ tq,
             short* __restrict__ q_states)
{
    const int tid = threadIdx.x, lane = tid & 63, w = tid >> 6;
    const int g = lane >> 4, l15 = lane & 15;
    const int bm = blockIdx.x / 3, ns = blockIdx.x % 3;
    const int m0 = bm * 16;
    const int nb = ns * 1024 + w * 256;

    short8 af[4];
    #pragma unroll
    for (int ks = 0; ks < 4; ++ks)
        af[ks] = *reinterpret_cast<const short8*>(
            cq_bf + (size_t)(m0 + l15) * 128 + ks * 32 + g * 8);

    float4v acc[16];
    #pragma unroll
    for (int nj = 0; nj < 16; ++nj) acc[nj] = (float4v){0.f, 0.f, 0.f, 0.f};

    #pragma unroll
    for (int ks = 0; ks < 4; ++ks)
        #pragma unroll
        for (int nj = 0; nj < 16; ++nj) {
            int j = nb + nj * 16 + l15;
            int h = j / 192, t = j - h * 192;
            const short* brow;
            if (t < 128)       brow = WqcombT + (size_t)h * 16384 + (size_t)t * 128;
            else if (t < 160)  brow = w_uqT + (size_t)(h * 96 + 64 + (t - 128)) * 128;
            else               brow = w_uqT + (size_t)(1536 + h * 32 + (t - 160)) * 128;
            short8 bf = *reinterpret_cast<const short8*>(brow + ks * 32 + g * 8);
            acc[nj] = __builtin_amdgcn_mfma_f32_16x16x32_bf16(af[ks], bf, acc[nj], 0, 0, 0);
        }

    #pragma unroll
    for (int nj = 0; nj < 16; ++nj) {
        int j = nb + nj * 16 + l15;
        int h = j / 192, t = j - h * 192;
        if (t < 160) {
            #pragma unroll
            for (int r = 0; r < 4; ++r) {
                int rg = m0 + g * 4 + r, bb = rg >> 11, spos = rg & (S_LEN - 1);
                q_states[((size_t)(bb * NH + h) * S_LEN + spos) * DQK + t] =
                    f2bf(acc[nj][r]);
            }
        } else {
            int dd = t - 160, i2 = dd >> 1;
            #pragma unroll
            for (int r = 0; r < 4; ++r) {
                int rg = m0 + g * 4 + r, bb = rg >> 11, spos = rg & (S_LEN - 1);
                float v = acc[nj][r];
                float p = __shfl_xor(v, 1, 64);
                float c  = tq[(spos * 16 + i2) * 2 + 0];
                float sn = tq[(spos * 16 + i2) * 2 + 1];
                float out = (dd & 1) ? (p * sn + v * c) : (v * c - p * sn);
                q_states[((size_t)(bb * NH + h) * S_LEN + spos) * DQK + t] = f2bf(out);
            }
        }
    }
}

// ---------------------------------------------------------------------------
// K4: absorbed-MLA swapped-QK 32x32 MFMA flash attention (R12-proven).
//   dqk=192 (12 QK MFMA), V = ckv (DV=128, 8 PV MFMA). kx images shared by
//   all heads. 512 blocks, 8 waves = 4 q-groups x 2 kv-halves, qtile 128,
//   KVBLK=64. LDS: K 3x24KB, V 2x16KB. Counted-vmcnt: [K(3),V(2),K(3)] ->
//   vmcnt(3). Output attn_out (B,S,H*128) bf16.
// ---------------------------------------------------------------------------
__global__ __launch_bounds__(512, 1)
void k4_attn_mfma(const short* __restrict__ q_states,
                  const short* __restrict__ kimg,
                  const short* __restrict__ vimg,
                  short* __restrict__ attn_out)
{
    __shared__ __align__(16) short ks_lds[3][12288];   // 3 x 24 KB
    __shared__ __align__(16) short vt_lds[2][8192];    // 2 x 16 KB

    const int tid = threadIdx.x, lane = tid & 63, w = tid >> 6;
    const int bid = blockIdx.x;
    const int l31 = lane & 31, hi = lane >> 5;
    const int g = w & 3, h = w >> 2;
    const int qt = (bid < 256) ? (15 - (bid >> 5)) : (7 - ((bid - 256) >> 5));
    const int bh = bid & 31;
    const int h_head = bh & 15, b = bh >> 4;

    const short* kfbase = kimg + (size_t)b * 32 * 12288;
    const short* vfbase = vimg + (size_t)b * 32 * 8192;

    const int qrow0 = qt * 128 + g * 32;
    const int qglob = qrow0 + l31;

    short8 qcur[12];
    {
        const short* qr = q_states +
            ((size_t)(b * NH + h_head) * S_LEN + qglob) * DQK + hi * 8;
        #pragma unroll
        for (int st = 0; st < 12; ++st)
            qcur[st] = *reinterpret_cast<const short8*>(qr + st * 16);
    }

    float16v o[4];
    #pragma unroll
    for (int dt = 0; dt < 4; ++dt)
        #pragma unroll
        for (int r = 0; r < 16; ++r) o[dt][r] = 0.f;
    float mreg = -1e30f, lreg = 0.f;

    const int nkt = 2 * (qt + 1);

    auto issueK = [&](int kt, int bufi) {
        const short* src = kfbase + (size_t)kt * 12288;
        #pragma unroll
        for (int i = 0; i < 3; ++i) {
            int c = w * 3 + i;
            gl_lds16(src + c * 512 + lane * 8, &ks_lds[bufi][c * 512]);
        }
    };
    auto issueV = [&](int kt, int bufi) {
        const short* src = vfbase + (size_t)kt * 8192;
        #pragma unroll
        for (int i = 0; i < 2; ++i) {
            int c = w * 2 + i;
            gl_lds16(src + c * 512 + lane * 8, &vt_lds[bufi][c * 512]);
        }
    };

    issueK(0, 0);
    issueV(0, 0);
    issueK(1, 1);

    for (int seq = 0; seq < nkt; ++seq) {
        if (seq < nkt - 1) { asm volatile("s_waitcnt vmcnt(3)" ::: "memory"); }
        else               { asm volatile("s_waitcnt vmcnt(0)" ::: "memory"); }
        __builtin_amdgcn_s_barrier();
        __builtin_amdgcn_sched_barrier(0);

        if (seq + 1 < nkt) issueV(seq + 1, (seq + 1) & 1);
        if (seq + 2 < nkt) issueK(seq + 2, (seq + 2) % 3);

        const int kvb = seq * 64 + h * 32;
        if (kvb <= qrow0 + 31) {
            const short* kbuf = &ks_lds[seq % 3][h * 6144];
            float16v sa, sb;
            #pragma unroll
            for (int r = 0; r < 16; ++r) { sa[r] = 0.f; sb[r] = 0.f; }
            __builtin_amdgcn_s_setprio(1);
            #pragma unroll
            for (int st = 0; st < 12; st += 2) {
                short8 kf0 = *reinterpret_cast<const short8*>(kbuf + st * 512 + lane * 8);
                sa = __builtin_amdgcn_mfma_f32_32x32x16_bf16(kf0, qcur[st], sa, 0, 0, 0);
                short8 kf1 = *reinterpret_cast<const short8*>(kbuf + (st + 1) * 512 + lane * 8);
                sb = __builtin_amdgcn_mfma_f32_32x32x16_bf16(kf1, qcur[st + 1], sb, 0, 0, 0);
            }
            __builtin_amdgcn_s_setprio(0);
            float16v s;
            #pragma unroll
            for (int r = 0; r < 16; ++r) s[r] = sa[r] + sb[r];

            if (kvb + 31 > qrow0) {
                #pragma unroll
                for (int r = 0; r < 16; ++r) {
                    int kc = kvb + ((r & 3) + 8 * (r >> 2) + 4 * hi);
                    if (kc > qglob) s[r] = -1e30f;
                }
            }

            float mx = s[0];
            #pragma unroll
            for (int r = 1; r < 16; ++r) mx = fmaxf(mx, s[r]);
            mx = fmaxf(mx, __shfl_xor(mx, 32, 64));
            bool need = mx > mreg + 8.f;
            if (__ballot(need)) {
                float mnew = fmaxf(mreg, mx);
                float corr = exp2f(mreg - mnew);
                mreg = mnew;
                lreg *= corr;
                #pragma unroll
                for (int dt = 0; dt < 4; ++dt)
                    #pragma unroll
                    for (int r = 0; r < 16; ++r) o[dt][r] *= corr;
            }
            #pragma unroll
            for (int r = 0; r < 16; ++r) s[r] = exp2f(s[r] - mreg);
            float ps = 0.f;
            #pragma unroll
            for (int r = 0; r < 16; ++r) ps += s[r];
            ps += __shfl_xor(ps, 32, 64);
            lreg += ps;

            const short* vbuf = &vt_lds[seq & 1][h * 1024];
            __builtin_amdgcn_s_setprio(1);
            #pragma unroll
            for (int ks = 0; ks < 2; ++ks) {
                const int rb = ks * 8;
                int c01, c23, c45, c67;
                asm("v_cvt_pk_bf16_f32 %0, %1, %2" : "=v"(c01) : "v"(s[rb+0]), "v"(s[rb+1]));
                asm("v_cvt_pk_bf16_f32 %0, %1, %2" : "=v"(c23) : "v"(s[rb+2]), "v"(s[rb+3]));
                asm("v_cvt_pk_bf16_f32 %0, %1, %2" : "=v"(c45) : "v"(s[rb+4]), "v"(s[rb+5]));
                asm("v_cvt_pk_bf16_f32 %0, %1, %2" : "=v"(c67) : "v"(s[rb+6]), "v"(s[rb+7]));
                asm("v_permlane32_swap_b32 %0, %1" : "+v"(c01), "+v"(c45));
                asm("v_permlane32_swap_b32 %0, %1" : "+v"(c23), "+v"(c67));
                union { int4v i4; short8 s8; } u_;
                u_.i4.x = c01; u_.i4.y = c23; u_.i4.z = c45; u_.i4.w = c67;
                short8 pa = u_.s8;
                #pragma unroll
                for (int dt = 0; dt < 4; ++dt) {
                    short8 vf = *reinterpret_cast<const short8*>(
                        vbuf + dt * 2048 + ks * 512 + lane * 8);
                    o[dt] = __builtin_amdgcn_mfma_f32_32x32x16_bf16(vf, pa, o[dt], 0, 0, 0);
                }
            }
            __builtin_amdgcn_s_setprio(0);
        }
    }

    __syncthreads();
    {
        float* mlb = (float*)(&ks_lds[0][0]);
        mlb[w * 64 + lane] = mreg;
        mlb[512 + w * 64 + lane] = lreg;
    }
    __syncthreads();
    float s0f = 0.f, s1f = 0.f;
    if (h == 0) {
        float* mlb = (float*)(&ks_lds[0][0]);
        float m1 = mlb[(w + 4) * 64 + lane];
        float l1 = mlb[512 + (w + 4) * 64 + lane];
        float ms = fmaxf(mreg, m1);
        float c0 = exp2f(mreg - ms), c1 = exp2f(m1 - ms);
        float ls = lreg * c0 + l1 * c1;
        s0f = c0 / ls; s1f = c1 / ls;
    }
    float* cb = (float*)(&ks_lds[0][0]) + 1024;
    short* obase = attn_out + ((size_t)(b * S_LEN + qglob)) * 2048 + h_head * 128;
    for (int dt = 0; dt < 4; ++dt) {
        __syncthreads();
        if (h == 1) {
            #pragma unroll
            for (int r = 0; r < 16; ++r)
                cb[r * 256 + g * 64 + lane] = o[dt][r];
        }
        __syncthreads();
        if (h == 0) {
            #pragma unroll
            for (int r = 0; r < 16; ++r)
                o[dt][r] = o[dt][r] * s0f + cb[r * 256 + g * 64 + lane] * s1f;
            #pragma unroll
            for (int k4i = 0; k4i < 4; ++k4i) {
                int d0 = dt * 32 + k4i * 8 + hi * 4;
                short4v pk;
                #pragma unroll
                for (int j = 0; j < 4; ++j) pk[j] = f2bf(o[dt][k4i * 4 + j]);
                *reinterpret_cast<short4v*>(obase + d0) = pk;
            }
        }
    }
}

// ---------------------------------------------------------------------------
// K5: out = attn_out (4096x2048 bf16) @ WcombT (2048x2048 bf16), f32 out.
// ---------------------------------------------------------------------------
__global__ __launch_bounds__(256)
void k5_gemm_mfma(const short* __restrict__ A,
                  const short* __restrict__ Bt,
                  float* __restrict__ C)
{
    __shared__ __align__(16) short at[128 * 64];
    __shared__ __align__(16) short bt[128 * 64];
    const int tid  = threadIdx.x;
    const int lane = tid & 63;
    const int wid  = tid >> 6;
    const int wm = wid >> 1, wn = wid & 1;
    const int g = lane >> 4, l15 = lane & 15;
    const int wg = (blockIdx.x & 7) * 64 + (blockIdx.x >> 3);   // XCD swizzle
    const int bn = wg & 15, bm = wg >> 4;
    const int m0 = bm * 128, n0 = bn * 128;

    float4v acc[4][4];
    #pragma unroll
    for (int mi = 0; mi < 4; ++mi)
        #pragma unroll
        for (int nj = 0; nj < 4; ++nj) acc[mi][nj] = (float4v){0.f, 0.f, 0.f, 0.f};

    for (int k0 = 0; k0 < 2048; k0 += 64) {
        __syncthreads();
        #pragma unroll
        for (int i = 0; i < 4; ++i) {
            int row = wid * 32 + i * 8 + (lane >> 3);
            int ch  = lane & 7;
            gl_lds16(A + (size_t)(m0 + row) * 2048 + k0 + ((ch ^ (row & 7)) * 8),
                     at + wid * 2048 + i * 512);
            gl_lds16(Bt + (size_t)(n0 + row) * 2048 + k0 + ((ch ^ (row & 7)) * 8),
                     bt + wid * 2048 + i * 512);
        }
        __syncthreads();

        #pragma unroll
        for (int kb = 0; kb < 2; ++kb) {
            short8 af[4], bfr[4];
            #pragma unroll
            for (int mi = 0; mi < 4; ++mi) {
                int row = wm * 64 + mi * 16 + l15;
                af[mi] = *reinterpret_cast<const short8*>(
                    at + row * 64 + (((g + 4 * kb) ^ (row & 7)) * 8));
            }
            #pragma unroll
            for (int nj = 0; nj < 4; ++nj) {
                int row = wn * 64 + nj * 16 + l15;
                bfr[nj] = *reinterpret_cast<const short8*>(
                    bt + row * 64 + (((g + 4 * kb) ^ (row & 7)) * 8));
            }
            #pragma unroll
            for (int mi = 0; mi < 4; ++mi)
                #pragma unroll
                for (int nj = 0; nj < 4; ++nj)
                    acc[mi][nj] = __builtin_amdgcn_mfma_f32_16x16x32_bf16(
                        af[mi], bfr[nj], acc[mi][nj], 0, 0, 0);
        }
    }

    #pragma unroll
    for (int mi = 0; mi < 4; ++mi)
        #pragma unroll
        for (int nj = 0; nj < 4; ++nj)
            #pragma unroll
            for (int r = 0; r < 4; ++r)
                C[(size_t)(m0 + wm * 64 + mi * 16 + g * 4 + r) * DIM + n0 + wn * 64 + nj * 16 + l15] =
                    acc[mi][nj][r];
}

// ---------------------------------------------------------------------------
extern "C" void kernel_launch(void* const* d_in, const int* in_sizes, int n_in,
                              void* d_out, int out_size, void* d_ws, size_t ws_size,
                              hipStream_t stream)
{
    const float* x        = (const float*)d_in[0];
    const float* w_dq     = (const float*)d_in[1];
    const float* gamma_q  = (const float*)d_in[2];
    const float* w_uq     = (const float*)d_in[3];
    const float* w_dkv    = (const float*)d_in[4];
    const float* gamma_kv = (const float*)d_in[5];
    const float* w_ukv    = (const float*)d_in[6];
    const float* w_o      = (const float*)d_in[7];
    float* out = (float*)d_out;

    char* ws = (char*)d_ws;
    short* cq_bf    = (short*)(ws);                       // 1 MB
    float* tq       = (float*)(ws + (1ull  << 20));       // 0.25 MB
    float* tk       = (float*)(ws + (2ull  << 20));       // 0.5 MB
    short* w_uqT    = (short*)(ws + (3ull  << 20));       // 0.5 MB
    short* wdT      = (short*)(ws + (4ull  << 20));       // 1.25 MB
    short* WqcombT  = (short*)(ws + (6ull  << 20));       // 0.5 MB
    short* kimg     = (short*)(ws + (7ull  << 20));       // 1.5 MB
    short* vimg     = (short*)(ws + (9ull  << 20));       // 1 MB
    short* q_states = (short*)(ws + (11ull << 20));       // 25.2 MB
    short* attn_out = (short*)(ws + (38ull << 20));       // 16 MB
    short* w_oT     = (short*)(ws + (54ull << 20));       // 16 MB
    short* WcombT   = (short*)(ws + (70ull << 20));       // 8 MB
    // total 78 MB

    kprep_all<<<dim3(2656), dim3(256), 0, stream>>>(
        w_o, w_uq, w_dq, w_dkv, w_oT, w_uqT, wdT, tq, tk);

    kcomb<<<dim3(272), dim3(256), 0, stream>>>(
        w_uq, w_ukv, w_oT, WqcombT, WcombT);

    k1_mfma<<<dim3(ROWS_TOT / 16), dim3(256), 0, stream>>>(
        x, wdT, gamma_q, gamma_kv, tk, cq_bf, kimg, vimg);

    k2_mfma<<<dim3((ROWS_TOT / 16) * 3), dim3(256), 0, stream>>>(
        cq_bf, WqcombT, w_uqT, tq, q_states);

    k4_attn_mfma<<<dim3(512), dim3(512), 0, stream>>>(
        q_states, kimg, vimg, attn_out);

    k5_gemm_mfma<<<dim3(512), dim3(256), 0, stream>>>(
        attn_out, WcombT, out);
}